// Round 1
// baseline (742.373 us; speedup 1.0000x reference)
//
#include <hip/hip_runtime.h>

#define N_NODES 100000
#define N_EDGES 20000
#define NNZ     1600000
#define D       128

// ---------------- zero ----------------
__global__ void k_zero(int* __restrict__ p, int n) {
  int i = blockIdx.x * 256 + threadIdx.x;
  if (i < n) p[i] = 0;
}

// ---------------- degrees ----------------
__global__ void k_degrees(const int* __restrict__ v_idx, const int* __restrict__ e_idx,
                          int* __restrict__ dv, int* __restrict__ de) {
  int i = blockIdx.x * 256 + threadIdx.x;
  if (i >= NNZ) return;
  atomicAdd(&dv[v_idx[i]], 1);
  atomicAdd(&de[e_idx[i]], 1);
}

// ---------------- hierarchical exclusive scan (chunk = 1024 = 256 thr x 4) ----------------
__global__ void k_block_sums(const int* __restrict__ src, int n, int* __restrict__ bsums) {
  __shared__ int sd[256];
  int base = blockIdx.x * 1024 + threadIdx.x * 4;
  int s = 0;
#pragma unroll
  for (int j = 0; j < 4; ++j) { int idx = base + j; if (idx < n) s += src[idx]; }
  sd[threadIdx.x] = s; __syncthreads();
  for (int off = 128; off > 0; off >>= 1) {
    if (threadIdx.x < off) sd[threadIdx.x] += sd[threadIdx.x + off];
    __syncthreads();
  }
  if (threadIdx.x == 0) bsums[blockIdx.x] = sd[0];
}

__global__ void k_scan_bsums(int* __restrict__ bsums, int nb) {
  __shared__ int sd[1024];
  int t = threadIdx.x;
  int x = (t < nb) ? bsums[t] : 0;
  sd[t] = x; __syncthreads();
  for (int off = 1; off < 1024; off <<= 1) {
    int add = (t >= off) ? sd[t - off] : 0;
    __syncthreads();
    sd[t] += add;
    __syncthreads();
  }
  if (t < nb) bsums[t] = sd[t] - x;   // exclusive
}

__global__ void k_scan_final(const int* __restrict__ src, int n, const int* __restrict__ bsums,
                             int* __restrict__ off_out, int* __restrict__ cur_out) {
  __shared__ int sd[256];
  int base = blockIdx.x * 1024 + threadIdx.x * 4;
  int v[4]; int s = 0;
#pragma unroll
  for (int j = 0; j < 4; ++j) { v[j] = (base + j < n) ? src[base + j] : 0; s += v[j]; }
  int own = s;
  sd[threadIdx.x] = s; __syncthreads();
  for (int off = 1; off < 256; off <<= 1) {
    int add = (threadIdx.x >= off) ? sd[threadIdx.x - off] : 0;
    __syncthreads();
    sd[threadIdx.x] += add;
    __syncthreads();
  }
  int run = bsums[blockIdx.x] + sd[threadIdx.x] - own;
#pragma unroll
  for (int j = 0; j < 4; ++j) {
    int idx = base + j;
    if (idx < n) {
      off_out[idx] = run; cur_out[idx] = run;
      run += v[j];
      if (idx == n - 1) off_out[n] = run;
    }
  }
}

// ---------------- per-element scale factors ----------------
__global__ void k_scales(const int* __restrict__ dv, const int* __restrict__ de,
                         float* __restrict__ risv, float* __restrict__ invde) {
  int i = blockIdx.x * 256 + threadIdx.x;
  if (i < N_NODES) { int d = dv[i]; risv[i] = d > 0 ? rsqrtf((float)d) : 0.0f; }
  if (i < N_EDGES) { int d = de[i]; invde[i] = d > 0 ? 1.0f / (float)d : 0.0f; }
}

// ---------------- CSR index build (atomic ticket) ----------------
__global__ void k_build(const int* __restrict__ v_idx, const int* __restrict__ e_idx,
                        int* __restrict__ vcur, int* __restrict__ ecur,
                        int* __restrict__ vlist, int* __restrict__ elist) {
  int i = blockIdx.x * 256 + threadIdx.x;
  if (i >= NNZ) return;
  int v = v_idx[i], e = e_idx[i];
  int pe = atomicAdd(&ecur[e], 1); elist[pe] = v;   // per-edge vertex list
  int pv = atomicAdd(&vcur[v], 1); vlist[pv] = e;   // per-vertex edge list
}

// ---------------- phase A: Qe[e] = sum_{v in e} risv[v] * X[v];  qv[e] = sum risv[v] ----------------
__global__ void k_edge_gather(const float* __restrict__ X, const float* __restrict__ risv,
                              const int* __restrict__ eoff, const int* __restrict__ elist,
                              float* __restrict__ Qe, float* __restrict__ qv) {
  int wid = (blockIdx.x * 256 + threadIdx.x) >> 6;   // one wave per edge
  int lane = threadIdx.x & 63;
  if (wid >= N_EDGES) return;
  int beg = eoff[wid], end = eoff[wid + 1];
  float ax = 0.f, ay = 0.f, q = 0.f;
  int i = beg;
  for (; i + 4 <= end; i += 4) {
    int v0 = elist[i], v1 = elist[i + 1], v2 = elist[i + 2], v3 = elist[i + 3];
    float r0 = risv[v0], r1 = risv[v1], r2 = risv[v2], r3 = risv[v3];
    float2 x0 = *(const float2*)(X + (size_t)v0 * D + lane * 2);
    float2 x1 = *(const float2*)(X + (size_t)v1 * D + lane * 2);
    float2 x2 = *(const float2*)(X + (size_t)v2 * D + lane * 2);
    float2 x3 = *(const float2*)(X + (size_t)v3 * D + lane * 2);
    ax += r0 * x0.x + r1 * x1.x + r2 * x2.x + r3 * x3.x;
    ay += r0 * x0.y + r1 * x1.y + r2 * x2.y + r3 * x3.y;
    q += r0 + r1 + r2 + r3;
  }
  for (; i < end; ++i) {
    int v = elist[i]; float r = risv[v];
    float2 x = *(const float2*)(X + (size_t)v * D + lane * 2);
    ax += r * x.x; ay += r * x.y; q += r;
  }
  float2 o; o.x = ax; o.y = ay;
  *(float2*)(Qe + (size_t)wid * D + lane * 2) = o;
  if (lane == 0) qv[wid] = q;
}

// ---------------- phase GEMM: Ye[e] = invde[e] * (Qe[e] @ W + qv[e] * b) ----------------
__global__ __launch_bounds__(256) void k_gemm(const float* __restrict__ Qe, const float* __restrict__ qv,
                                              const float* __restrict__ W, const float* __restrict__ bias,
                                              const float* __restrict__ invde, float* __restrict__ Ye) {
  __shared__ float Wl[D * D];
  __shared__ float bl[D];
  __shared__ float Ql[16][130];
  int tid = threadIdx.x;
  const float4* W4 = (const float4*)W;
  float4* Wl4 = (float4*)Wl;
#pragma unroll
  for (int j = 0; j < 16; ++j) Wl4[tid + 256 * j] = W4[tid + 256 * j];   // 4096 float4 = 16K floats
  if (tid < 32) ((float4*)bl)[tid] = ((const float4*)bias)[tid];
  int row0 = blockIdx.x * 16;
  const float4* Q4 = (const float4*)(Qe + (size_t)row0 * D);
#pragma unroll
  for (int j = 0; j < 2; ++j) {
    int idx = tid + 256 * j;          // 0..511  (16 rows x 32 float4)
    int r = idx >> 5, c4 = idx & 31;
    float4 val = Q4[idx];
    Ql[r][c4 * 4 + 0] = val.x; Ql[r][c4 * 4 + 1] = val.y;
    Ql[r][c4 * 4 + 2] = val.z; Ql[r][c4 * 4 + 3] = val.w;
  }
  __syncthreads();
  int ty = tid >> 4;    // row 0..15
  int tx = tid & 15;    // col group: cols 8*tx .. 8*tx+7
  float acc[8];
#pragma unroll
  for (int j = 0; j < 8; ++j) acc[j] = 0.f;
#pragma unroll 4
  for (int k = 0; k < D; ++k) {
    float xv = Ql[ty][k];
    const float* wr = Wl + k * D + tx * 8;
#pragma unroll
    for (int j = 0; j < 8; ++j) acc[j] += xv * wr[j];
  }
  int row = row0 + ty;
  float s = invde[row]; float q = qv[row];
  float* orow = Ye + (size_t)row * D + tx * 8;
#pragma unroll
  for (int j = 0; j < 8; ++j) orow[j] = s * (acc[j] + q * bl[tx * 8 + j]);
}

// ---------------- phase B: out[v] = relu(risv[v] * sum_{e ni v} Ye[e]) ----------------
__global__ void k_vertex_gather(const float* __restrict__ Ye, const float* __restrict__ risv,
                                const int* __restrict__ voff, const int* __restrict__ vlist,
                                float* __restrict__ out) {
  int wid = (blockIdx.x * 256 + threadIdx.x) >> 6;   // one wave per vertex
  int lane = threadIdx.x & 63;
  if (wid >= N_NODES) return;
  int beg = voff[wid], end = voff[wid + 1];
  float ax = 0.f, ay = 0.f;
  int i = beg;
  for (; i + 4 <= end; i += 4) {
    int e0 = vlist[i], e1 = vlist[i + 1], e2 = vlist[i + 2], e3 = vlist[i + 3];
    float2 y0 = *(const float2*)(Ye + (size_t)e0 * D + lane * 2);
    float2 y1 = *(const float2*)(Ye + (size_t)e1 * D + lane * 2);
    float2 y2 = *(const float2*)(Ye + (size_t)e2 * D + lane * 2);
    float2 y3 = *(const float2*)(Ye + (size_t)e3 * D + lane * 2);
    ax += y0.x + y1.x + y2.x + y3.x;
    ay += y0.y + y1.y + y2.y + y3.y;
  }
  for (; i < end; ++i) {
    int e = vlist[i];
    float2 y = *(const float2*)(Ye + (size_t)e * D + lane * 2);
    ax += y.x; ay += y.y;
  }
  float s = risv[wid];
  float2 o; o.x = fmaxf(ax * s, 0.f); o.y = fmaxf(ay * s, 0.f);
  *(float2*)(out + (size_t)wid * D + lane * 2) = o;
}

extern "C" void kernel_launch(void* const* d_in, const int* in_sizes, int n_in,
                              void* d_out, int out_size, void* d_ws, size_t ws_size,
                              hipStream_t stream) {
  const float* X    = (const float*)d_in[0];
  const float* W    = (const float*)d_in[1];
  const float* bias = (const float*)d_in[2];
  const int* v_idx  = (const int*)d_in[3];
  const int* e_idx  = (const int*)d_in[4];
  float* out = (float*)d_out;

  char* p = (char*)d_ws;
  auto alloc = [&](size_t bytes) { char* r = p; p += (bytes + 255) & ~(size_t)255; return r; };
  float* Qe    = (float*)alloc((size_t)N_EDGES * D * 4);
  float* Ye    = (float*)alloc((size_t)N_EDGES * D * 4);
  float* qv    = (float*)alloc((size_t)N_EDGES * 4);
  float* risv  = (float*)alloc((size_t)N_NODES * 4);
  float* invde = (float*)alloc((size_t)N_EDGES * 4);
  int* dv    = (int*)alloc((size_t)(N_NODES + N_EDGES) * 4);
  int* de    = dv + N_NODES;
  int* voff  = (int*)alloc((size_t)(N_NODES + 1) * 4);
  int* eoff  = (int*)alloc((size_t)(N_EDGES + 1) * 4);
  int* vcur  = (int*)alloc((size_t)N_NODES * 4);
  int* ecur  = (int*)alloc((size_t)N_EDGES * 4);
  int* vlist = (int*)alloc((size_t)NNZ * 4);
  int* elist = (int*)alloc((size_t)NNZ * 4);
  int* bsV   = (int*)alloc(1024 * 4);
  int* bsE   = (int*)alloc(1024 * 4);

  int nbV = (N_NODES + 1023) / 1024;   // 98
  int nbE = (N_EDGES + 1023) / 1024;   // 20

  k_zero<<<(N_NODES + N_EDGES + 255) / 256, 256, 0, stream>>>(dv, N_NODES + N_EDGES);
  k_degrees<<<NNZ / 256, 256, 0, stream>>>(v_idx, e_idx, dv, de);

  k_block_sums<<<nbE, 256, 0, stream>>>(de, N_EDGES, bsE);
  k_scan_bsums<<<1, 1024, 0, stream>>>(bsE, nbE);
  k_scan_final<<<nbE, 256, 0, stream>>>(de, N_EDGES, bsE, eoff, ecur);

  k_block_sums<<<nbV, 256, 0, stream>>>(dv, N_NODES, bsV);
  k_scan_bsums<<<1, 1024, 0, stream>>>(bsV, nbV);
  k_scan_final<<<nbV, 256, 0, stream>>>(dv, N_NODES, bsV, voff, vcur);

  k_scales<<<(N_NODES + 255) / 256, 256, 0, stream>>>(dv, de, risv, invde);
  k_build<<<NNZ / 256, 256, 0, stream>>>(v_idx, e_idx, vcur, ecur, vlist, elist);

  k_edge_gather<<<N_EDGES / 4, 256, 0, stream>>>(X, risv, eoff, elist, Qe, qv);
  k_gemm<<<N_EDGES / 16, 256, 0, stream>>>(Qe, qv, W, bias, invde, Ye);
  k_vertex_gather<<<N_NODES / 4, 256, 0, stream>>>(Ye, risv, voff, vlist, out);
}

// Round 2
// 385.953 us; speedup vs baseline: 1.9235x; 1.9235x over previous
//
#include <hip/hip_runtime.h>

#define N_NODES 100000
#define N_EDGES 20000
#define NNZ     1600000
#define D       128

#define NB      256                        // buckets per side
#define CAP_E   8192                       // bucket capacity (pairs); mean 6250, +24 sigma
#define CAP_V   8192
#define SPAN_E  ((N_EDGES + NB - 1) / NB)  // 79 edges per bucket
#define SPAN_V  ((N_NODES + NB - 1) / NB)  // 391 vertices per bucket
#define P1_CHUNK 8192
#define P1_BLOCKS ((NNZ + P1_CHUNK - 1) / P1_CHUNK)  // 196

// ---------------- init bucket cursors ----------------
__global__ void k_init(int* __restrict__ ce, int* __restrict__ cv) {
  int t = threadIdx.x;
  ce[t] = t * CAP_E;
  cv[t] = t * CAP_V;
}

// ---------------- pass 1: bin incidences by e-bucket and v-bucket ----------------
__global__ __launch_bounds__(256) void k_bin(const int* __restrict__ v_idx, const int* __restrict__ e_idx,
                                             int* __restrict__ ce, int* __restrict__ cv,
                                             unsigned int* __restrict__ Te, unsigned int* __restrict__ Tv) {
  __shared__ int he[NB], hv[NB], be[NB], bv[NB], le[NB], lv[NB];
  int t = threadIdx.x;
  he[t] = 0; hv[t] = 0; le[t] = 0; lv[t] = 0;
  __syncthreads();
  int base = blockIdx.x * P1_CHUNK;
  int v[32], e[32];
#pragma unroll
  for (int j = 0; j < 32; ++j) {
    int idx = base + j * 256 + t;
    if (idx < NNZ) {
      v[j] = v_idx[idx]; e[j] = e_idx[idx];
      atomicAdd(&he[e[j] / SPAN_E], 1);
      atomicAdd(&hv[v[j] / SPAN_V], 1);
    } else v[j] = -1;
  }
  __syncthreads();
  be[t] = he[t] ? atomicAdd(&ce[t], he[t]) : 0;
  bv[t] = hv[t] ? atomicAdd(&cv[t], hv[t]) : 0;
  __syncthreads();
#pragma unroll
  for (int j = 0; j < 32; ++j) {
    if (v[j] < 0) continue;
    int eb = e[j] / SPAN_E, vb = v[j] / SPAN_V;
    int se = be[eb] + atomicAdd(&le[eb], 1);
    int sv = bv[vb] + atomicAdd(&lv[vb], 1);
    if (se < (eb + 1) * CAP_E) Te[se] = ((unsigned)e[j] << 17) | (unsigned)v[j];
    if (sv < (vb + 1) * CAP_V) Tv[sv] = ((unsigned)v[j] << 15) | (unsigned)e[j];
  }
}

// ---------------- pass 2 (edge side): per-bucket counting sort + degrees ----------------
__global__ __launch_bounds__(256) void k_sort_e(const int* __restrict__ ce, unsigned int* __restrict__ Te,
                                                int* __restrict__ cnt_e, float* __restrict__ invde,
                                                int* __restrict__ starts_e) {
  __shared__ unsigned int raw[CAP_E];
  __shared__ int hist[SPAN_E], lcur[SPAN_E], loff[SPAN_E + 1];
  int b = blockIdx.x, t = threadIdx.x;
  int e0 = b * SPAN_E;
  int span = N_EDGES - e0; if (span > SPAN_E) span = SPAN_E;
  if (span <= 0) return;
  int n = ce[b] - b * CAP_E; if (n > CAP_E) n = CAP_E; if (n < 0) n = 0;
  for (int i = t; i < n; i += 256) raw[i] = Te[b * CAP_E + i];
  for (int i = t; i < span; i += 256) { hist[i] = 0; lcur[i] = 0; }
  __syncthreads();
  for (int i = t; i < n; i += 256) atomicAdd(&hist[(int)(raw[i] >> 17) - e0], 1);
  __syncthreads();
  if (t == 0) { int run = 0; for (int i = 0; i < span; ++i) { loff[i] = run; run += hist[i]; } loff[span] = run; }
  __syncthreads();
  for (int i = t; i < n; i += 256) {
    unsigned int p = raw[i];
    int l = (int)(p >> 17) - e0;
    int slot = loff[l] + atomicAdd(&lcur[l], 1);
    Te[b * CAP_E + slot] = p & 0x1FFFFu;      // sorted member list: vertex ids
  }
  for (int i = t; i < span; i += 256) {
    int d = hist[i];
    cnt_e[e0 + i] = d;
    invde[e0 + i] = d > 0 ? 1.0f / (float)d : 0.0f;
    starts_e[e0 + i] = b * CAP_E + loff[i];
  }
}

// ---------------- pass 2 (vertex side) ----------------
__global__ __launch_bounds__(256) void k_sort_v(const int* __restrict__ cv, unsigned int* __restrict__ Tv,
                                                int* __restrict__ cnt_v, float* __restrict__ risv,
                                                int* __restrict__ starts_v) {
  __shared__ unsigned int raw[CAP_V];
  __shared__ int hist[SPAN_V], lcur[SPAN_V], loff[SPAN_V + 1];
  int b = blockIdx.x, t = threadIdx.x;
  int v0 = b * SPAN_V;
  int span = N_NODES - v0; if (span > SPAN_V) span = SPAN_V;
  if (span <= 0) return;
  int n = cv[b] - b * CAP_V; if (n > CAP_V) n = CAP_V; if (n < 0) n = 0;
  for (int i = t; i < n; i += 256) raw[i] = Tv[b * CAP_V + i];
  for (int i = t; i < span; i += 256) { hist[i] = 0; lcur[i] = 0; }
  __syncthreads();
  for (int i = t; i < n; i += 256) atomicAdd(&hist[(int)(raw[i] >> 15) - v0], 1);
  __syncthreads();
  if (t == 0) { int run = 0; for (int i = 0; i < span; ++i) { loff[i] = run; run += hist[i]; } loff[span] = run; }
  __syncthreads();
  for (int i = t; i < n; i += 256) {
    unsigned int p = raw[i];
    int l = (int)(p >> 15) - v0;
    int slot = loff[l] + atomicAdd(&lcur[l], 1);
    Tv[b * CAP_V + slot] = p & 0x7FFFu;       // sorted member list: edge ids
  }
  for (int i = t; i < span; i += 256) {
    int d = hist[i];
    cnt_v[v0 + i] = d;
    risv[v0 + i] = d > 0 ? rsqrtf((float)d) : 0.0f;
    starts_v[v0 + i] = b * CAP_V + loff[i];
  }
}

// ---------------- phase A: Qe[e] = sum_{v in e} risv[v] * X[v];  qv[e] = sum risv[v] ----------------
__global__ void k_edge_gather(const float* __restrict__ X, const float* __restrict__ risv,
                              const int* __restrict__ starts_e, const int* __restrict__ cnt_e,
                              const unsigned int* __restrict__ members,
                              float* __restrict__ Qe, float* __restrict__ qv) {
  int wid = (blockIdx.x * 256 + threadIdx.x) >> 6;   // one wave per edge
  int lane = threadIdx.x & 63;
  if (wid >= N_EDGES) return;
  int beg = starts_e[wid], end = beg + cnt_e[wid];
  float ax = 0.f, ay = 0.f, q = 0.f;
  int i = beg;
  for (; i + 4 <= end; i += 4) {
    int v0 = members[i], v1 = members[i + 1], v2 = members[i + 2], v3 = members[i + 3];
    float r0 = risv[v0], r1 = risv[v1], r2 = risv[v2], r3 = risv[v3];
    float2 x0 = *(const float2*)(X + (size_t)v0 * D + lane * 2);
    float2 x1 = *(const float2*)(X + (size_t)v1 * D + lane * 2);
    float2 x2 = *(const float2*)(X + (size_t)v2 * D + lane * 2);
    float2 x3 = *(const float2*)(X + (size_t)v3 * D + lane * 2);
    ax += r0 * x0.x + r1 * x1.x + r2 * x2.x + r3 * x3.x;
    ay += r0 * x0.y + r1 * x1.y + r2 * x2.y + r3 * x3.y;
    q += r0 + r1 + r2 + r3;
  }
  for (; i < end; ++i) {
    int v = members[i]; float r = risv[v];
    float2 x = *(const float2*)(X + (size_t)v * D + lane * 2);
    ax += r * x.x; ay += r * x.y; q += r;
  }
  float2 o; o.x = ax; o.y = ay;
  *(float2*)(Qe + (size_t)wid * D + lane * 2) = o;
  if (lane == 0) qv[wid] = q;
}

// ---------------- GEMM: Ye[e] = invde[e] * (Qe[e] @ W + qv[e] * b) ----------------
__global__ __launch_bounds__(256) void k_gemm(const float* __restrict__ Qe, const float* __restrict__ qv,
                                              const float* __restrict__ W, const float* __restrict__ bias,
                                              const float* __restrict__ invde, float* __restrict__ Ye) {
  __shared__ float Wl[D * D];
  __shared__ float bl[D];
  __shared__ float Ql[16][130];
  int tid = threadIdx.x;
  const float4* W4 = (const float4*)W;
  float4* Wl4 = (float4*)Wl;
#pragma unroll
  for (int j = 0; j < 16; ++j) Wl4[tid + 256 * j] = W4[tid + 256 * j];
  if (tid < 32) ((float4*)bl)[tid] = ((const float4*)bias)[tid];
  int row0 = blockIdx.x * 16;
  const float4* Q4 = (const float4*)(Qe + (size_t)row0 * D);
#pragma unroll
  for (int j = 0; j < 2; ++j) {
    int idx = tid + 256 * j;
    int r = idx >> 5, c4 = idx & 31;
    float4 val = Q4[idx];
    Ql[r][c4 * 4 + 0] = val.x; Ql[r][c4 * 4 + 1] = val.y;
    Ql[r][c4 * 4 + 2] = val.z; Ql[r][c4 * 4 + 3] = val.w;
  }
  __syncthreads();
  int ty = tid >> 4, tx = tid & 15;
  float acc[8];
#pragma unroll
  for (int j = 0; j < 8; ++j) acc[j] = 0.f;
#pragma unroll 4
  for (int k = 0; k < D; ++k) {
    float xv = Ql[ty][k];
    const float* wr = Wl + k * D + tx * 8;
#pragma unroll
    for (int j = 0; j < 8; ++j) acc[j] += xv * wr[j];
  }
  int row = row0 + ty;
  float s = invde[row]; float q = qv[row];
  float* orow = Ye + (size_t)row * D + tx * 8;
#pragma unroll
  for (int j = 0; j < 8; ++j) orow[j] = s * (acc[j] + q * bl[tx * 8 + j]);
}

// ---------------- phase B: out[v] = relu(risv[v] * sum_{e ni v} Ye[e]) ----------------
__global__ void k_vertex_gather(const float* __restrict__ Ye, const float* __restrict__ risv,
                                const int* __restrict__ starts_v, const int* __restrict__ cnt_v,
                                const unsigned int* __restrict__ members,
                                float* __restrict__ out) {
  int wid = (blockIdx.x * 256 + threadIdx.x) >> 6;   // one wave per vertex
  int lane = threadIdx.x & 63;
  if (wid >= N_NODES) return;
  int beg = starts_v[wid], end = beg + cnt_v[wid];
  float ax = 0.f, ay = 0.f;
  int i = beg;
  for (; i + 4 <= end; i += 4) {
    int e0 = members[i], e1 = members[i + 1], e2 = members[i + 2], e3 = members[i + 3];
    float2 y0 = *(const float2*)(Ye + (size_t)e0 * D + lane * 2);
    float2 y1 = *(const float2*)(Ye + (size_t)e1 * D + lane * 2);
    float2 y2 = *(const float2*)(Ye + (size_t)e2 * D + lane * 2);
    float2 y3 = *(const float2*)(Ye + (size_t)e3 * D + lane * 2);
    ax += y0.x + y1.x + y2.x + y3.x;
    ay += y0.y + y1.y + y2.y + y3.y;
  }
  for (; i < end; ++i) {
    int e = members[i];
    float2 y = *(const float2*)(Ye + (size_t)e * D + lane * 2);
    ax += y.x; ay += y.y;
  }
  float s = risv[wid];
  float2 o; o.x = fmaxf(ax * s, 0.f); o.y = fmaxf(ay * s, 0.f);
  *(float2*)(out + (size_t)wid * D + lane * 2) = o;
}

extern "C" void kernel_launch(void* const* d_in, const int* in_sizes, int n_in,
                              void* d_out, int out_size, void* d_ws, size_t ws_size,
                              hipStream_t stream) {
  const float* X    = (const float*)d_in[0];
  const float* W    = (const float*)d_in[1];
  const float* bias = (const float*)d_in[2];
  const int* v_idx  = (const int*)d_in[3];
  const int* e_idx  = (const int*)d_in[4];
  float* out = (float*)d_out;

  char* p = (char*)d_ws;
  auto alloc = [&](size_t bytes) { char* r = p; p += (bytes + 255) & ~(size_t)255; return r; };
  unsigned int* Te = (unsigned int*)alloc((size_t)NB * CAP_E * 4);
  unsigned int* Tv = (unsigned int*)alloc((size_t)NB * CAP_V * 4);
  float* Qe    = (float*)alloc((size_t)N_EDGES * D * 4);
  float* Ye    = (float*)alloc((size_t)N_EDGES * D * 4);
  float* qv    = (float*)alloc((size_t)N_EDGES * 4);
  float* risv  = (float*)alloc((size_t)N_NODES * 4);
  float* invde = (float*)alloc((size_t)N_EDGES * 4);
  int* cnt_e    = (int*)alloc((size_t)N_EDGES * 4);
  int* cnt_v    = (int*)alloc((size_t)N_NODES * 4);
  int* starts_e = (int*)alloc((size_t)N_EDGES * 4);
  int* starts_v = (int*)alloc((size_t)N_NODES * 4);
  int* ce       = (int*)alloc(NB * 4);
  int* cv       = (int*)alloc(NB * 4);

  k_init<<<1, NB, 0, stream>>>(ce, cv);
  k_bin<<<P1_BLOCKS, 256, 0, stream>>>(v_idx, e_idx, ce, cv, Te, Tv);
  k_sort_e<<<NB, 256, 0, stream>>>(ce, Te, cnt_e, invde, starts_e);
  k_sort_v<<<NB, 256, 0, stream>>>(cv, Tv, cnt_v, risv, starts_v);

  k_edge_gather<<<N_EDGES / 4, 256, 0, stream>>>(X, risv, starts_e, cnt_e, Te, Qe, qv);
  k_gemm<<<N_EDGES / 16, 256, 0, stream>>>(Qe, qv, W, bias, invde, Ye);
  k_vertex_gather<<<N_NODES / 4, 256, 0, stream>>>(Ye, risv, starts_v, cnt_v, Tv, out);
}

// Round 3
// 309.032 us; speedup vs baseline: 2.4023x; 1.2489x over previous
//
#include <hip/hip_runtime.h>

#define N_NODES 100000
#define N_EDGES 20000
#define NNZ     1600000
#define D       128
#define DW      64                         // uints per bf16 row (2 ch per uint)

#define NB      256                        // buckets per side
#define CAP_E   8192
#define CAP_V   8192
#define SPAN_E  ((N_EDGES + NB - 1) / NB)  // 79
#define SPAN_V  ((N_NODES + NB - 1) / NB)  // 391
#define P1_CHUNK 8192
#define P1_BLOCKS ((NNZ + P1_CHUNK - 1) / P1_CHUNK)

__device__ __forceinline__ unsigned int pack_bf2(float lo, float hi) {
  unsigned int ul = __float_as_uint(lo), uh = __float_as_uint(hi);
  ul = (ul + 0x7FFFu + ((ul >> 16) & 1u)) >> 16;
  uh = (uh + 0x7FFFu + ((uh >> 16) & 1u)) & 0xFFFF0000u;
  return ul | uh;
}

// ---------------- init bucket cursors ----------------
__global__ void k_init(int* __restrict__ ce, int* __restrict__ cv) {
  int t = threadIdx.x;
  ce[t] = t * CAP_E;
  cv[t] = t * CAP_V;
}

// ---------------- pass 1: bin incidences ----------------
__global__ __launch_bounds__(256) void k_bin(const int* __restrict__ v_idx, const int* __restrict__ e_idx,
                                             int* __restrict__ ce, int* __restrict__ cv,
                                             unsigned int* __restrict__ Te, unsigned int* __restrict__ Tv) {
  __shared__ int he[NB], hv[NB], be[NB], bv[NB], le[NB], lv[NB];
  int t = threadIdx.x;
  he[t] = 0; hv[t] = 0; le[t] = 0; lv[t] = 0;
  __syncthreads();
  int base = blockIdx.x * P1_CHUNK;
  int v[32], e[32];
#pragma unroll
  for (int j = 0; j < 32; ++j) {
    int idx = base + j * 256 + t;
    if (idx < NNZ) {
      v[j] = v_idx[idx]; e[j] = e_idx[idx];
      atomicAdd(&he[e[j] / SPAN_E], 1);
      atomicAdd(&hv[v[j] / SPAN_V], 1);
    } else v[j] = -1;
  }
  __syncthreads();
  be[t] = he[t] ? atomicAdd(&ce[t], he[t]) : 0;
  bv[t] = hv[t] ? atomicAdd(&cv[t], hv[t]) : 0;
  __syncthreads();
#pragma unroll
  for (int j = 0; j < 32; ++j) {
    if (v[j] < 0) continue;
    int eb = e[j] / SPAN_E, vb = v[j] / SPAN_V;
    int se = be[eb] + atomicAdd(&le[eb], 1);
    int sv = bv[vb] + atomicAdd(&lv[vb], 1);
    if (se < (eb + 1) * CAP_E) Te[se] = ((unsigned)e[j] << 17) | (unsigned)v[j];
    if (sv < (vb + 1) * CAP_V) Tv[sv] = ((unsigned)v[j] << 15) | (unsigned)e[j];
  }
}

// ---------------- pass 2 (edge side) ----------------
__global__ __launch_bounds__(256) void k_sort_e(const int* __restrict__ ce, unsigned int* __restrict__ Te,
                                                int* __restrict__ cnt_e, float* __restrict__ invde,
                                                int* __restrict__ starts_e) {
  __shared__ unsigned int raw[CAP_E];
  __shared__ int hist[SPAN_E], lcur[SPAN_E], loff[SPAN_E + 1];
  int b = blockIdx.x, t = threadIdx.x;
  int e0 = b * SPAN_E;
  int span = N_EDGES - e0; if (span > SPAN_E) span = SPAN_E;
  if (span <= 0) return;
  int n = ce[b] - b * CAP_E; if (n > CAP_E) n = CAP_E; if (n < 0) n = 0;
  for (int i = t; i < n; i += 256) raw[i] = Te[b * CAP_E + i];
  for (int i = t; i < span; i += 256) { hist[i] = 0; lcur[i] = 0; }
  __syncthreads();
  for (int i = t; i < n; i += 256) atomicAdd(&hist[(int)(raw[i] >> 17) - e0], 1);
  __syncthreads();
  if (t == 0) { int run = 0; for (int i = 0; i < span; ++i) { loff[i] = run; run += hist[i]; } loff[span] = run; }
  __syncthreads();
  for (int i = t; i < n; i += 256) {
    unsigned int p = raw[i];
    int l = (int)(p >> 17) - e0;
    int slot = loff[l] + atomicAdd(&lcur[l], 1);
    Te[b * CAP_E + slot] = p & 0x1FFFFu;
  }
  for (int i = t; i < span; i += 256) {
    int d = hist[i];
    cnt_e[e0 + i] = d;
    invde[e0 + i] = d > 0 ? 1.0f / (float)d : 0.0f;
    starts_e[e0 + i] = b * CAP_E + loff[i];
  }
}

// ---------------- pass 2 (vertex side) ----------------
__global__ __launch_bounds__(256) void k_sort_v(const int* __restrict__ cv, unsigned int* __restrict__ Tv,
                                                int* __restrict__ cnt_v, float* __restrict__ risv,
                                                int* __restrict__ starts_v) {
  __shared__ unsigned int raw[CAP_V];
  __shared__ int hist[SPAN_V], lcur[SPAN_V], loff[SPAN_V + 1];
  int b = blockIdx.x, t = threadIdx.x;
  int v0 = b * SPAN_V;
  int span = N_NODES - v0; if (span > SPAN_V) span = SPAN_V;
  if (span <= 0) return;
  int n = cv[b] - b * CAP_V; if (n > CAP_V) n = CAP_V; if (n < 0) n = 0;
  for (int i = t; i < n; i += 256) raw[i] = Tv[b * CAP_V + i];
  for (int i = t; i < span; i += 256) { hist[i] = 0; lcur[i] = 0; }
  __syncthreads();
  for (int i = t; i < n; i += 256) atomicAdd(&hist[(int)(raw[i] >> 15) - v0], 1);
  __syncthreads();
  if (t == 0) { int run = 0; for (int i = 0; i < span; ++i) { loff[i] = run; run += hist[i]; } loff[span] = run; }
  __syncthreads();
  for (int i = t; i < n; i += 256) {
    unsigned int p = raw[i];
    int l = (int)(p >> 15) - v0;
    int slot = loff[l] + atomicAdd(&lcur[l], 1);
    Tv[b * CAP_V + slot] = p & 0x7FFFu;
  }
  for (int i = t; i < span; i += 256) {
    int d = hist[i];
    cnt_v[v0 + i] = d;
    risv[v0 + i] = d > 0 ? rsqrtf((float)d) : 0.0f;
    starts_v[v0 + i] = b * CAP_V + loff[i];
  }
}

// ---------------- prescale: Xs[v] = bf16(risv[v] * X[v]) ----------------
__global__ __launch_bounds__(256) void k_prescale(const float* __restrict__ X, const float* __restrict__ risv,
                                                  unsigned int* __restrict__ Xs) {
  int p = blockIdx.x * 256 + threadIdx.x;           // uint index, [0, N_NODES*DW)
  if (p >= N_NODES * DW) return;
  int v = p >> 6;
  float r = risv[v];
  float2 x = *(const float2*)(X + (size_t)p * 2);
  Xs[p] = pack_bf2(r * x.x, r * x.y);
}

// ---------------- phase A: Qe[e] = sum Xs[v];  qv[e] = sum risv[v] ----------------
__global__ void k_edge_gather(const unsigned int* __restrict__ Xs, const float* __restrict__ risv,
                              const int* __restrict__ starts_e, const int* __restrict__ cnt_e,
                              const unsigned int* __restrict__ members,
                              float* __restrict__ Qe, float* __restrict__ qv) {
  int wid = (blockIdx.x * 256 + threadIdx.x) >> 6;   // one wave per edge
  int lane = threadIdx.x & 63;
  if (wid >= N_EDGES) return;
  int beg = __builtin_amdgcn_readfirstlane(starts_e[wid]);
  int end = beg + __builtin_amdgcn_readfirstlane(cnt_e[wid]);
  float ax = 0.f, ay = 0.f, q = 0.f;
  int i = beg;
  for (; i + 8 <= end; i += 8) {
    int vv[8]; unsigned int xx[8];
#pragma unroll
    for (int j = 0; j < 8; ++j) vv[j] = members[i + j];
#pragma unroll
    for (int j = 0; j < 8; ++j) xx[j] = Xs[(size_t)vv[j] * DW + lane];
#pragma unroll
    for (int j = 0; j < 8; ++j) q += risv[vv[j]];
#pragma unroll
    for (int j = 0; j < 8; ++j) {
      ax += __uint_as_float(xx[j] << 16);
      ay += __uint_as_float(xx[j] & 0xFFFF0000u);
    }
  }
  for (; i < end; ++i) {
    int v = members[i];
    unsigned int x = Xs[(size_t)v * DW + lane];
    ax += __uint_as_float(x << 16);
    ay += __uint_as_float(x & 0xFFFF0000u);
    q += risv[v];
  }
  float2 o; o.x = ax; o.y = ay;
  *(float2*)(Qe + (size_t)wid * D + lane * 2) = o;
  if (lane == 0) qv[wid] = q;
}

// ---------------- GEMM: Yeb[e] = bf16( invde[e] * (Qe[e] @ W + qv[e] * b) ) ----------------
__global__ __launch_bounds__(256) void k_gemm(const float* __restrict__ Qe, const float* __restrict__ qv,
                                              const float* __restrict__ W, const float* __restrict__ bias,
                                              const float* __restrict__ invde, unsigned int* __restrict__ Yeb) {
  __shared__ float Wl[D * D];
  __shared__ float bl[D];
  __shared__ float Ql[16][130];
  int tid = threadIdx.x;
  const float4* W4 = (const float4*)W;
  float4* Wl4 = (float4*)Wl;
#pragma unroll
  for (int j = 0; j < 16; ++j) Wl4[tid + 256 * j] = W4[tid + 256 * j];
  if (tid < 32) ((float4*)bl)[tid] = ((const float4*)bias)[tid];
  int row0 = blockIdx.x * 16;
  const float4* Q4 = (const float4*)(Qe + (size_t)row0 * D);
#pragma unroll
  for (int j = 0; j < 2; ++j) {
    int idx = tid + 256 * j;
    int r = idx >> 5, c4 = idx & 31;
    float4 val = Q4[idx];
    Ql[r][c4 * 4 + 0] = val.x; Ql[r][c4 * 4 + 1] = val.y;
    Ql[r][c4 * 4 + 2] = val.z; Ql[r][c4 * 4 + 3] = val.w;
  }
  __syncthreads();
  int ty = tid >> 4, tx = tid & 15;
  float acc[8];
#pragma unroll
  for (int j = 0; j < 8; ++j) acc[j] = 0.f;
#pragma unroll 4
  for (int k = 0; k < D; ++k) {
    float xv = Ql[ty][k];
    const float* wr = Wl + k * D + tx * 8;
#pragma unroll
    for (int j = 0; j < 8; ++j) acc[j] += xv * wr[j];
  }
  int row = row0 + ty;
  float s = invde[row]; float q = qv[row];
  unsigned int* orow = Yeb + (size_t)row * DW + tx * 4;
#pragma unroll
  for (int j = 0; j < 4; ++j) {
    float lo = s * (acc[2 * j]     + q * bl[tx * 8 + 2 * j]);
    float hi = s * (acc[2 * j + 1] + q * bl[tx * 8 + 2 * j + 1]);
    orow[j] = pack_bf2(lo, hi);
  }
}

// ---------------- phase B: out[v] = relu(risv[v] * sum Yeb[e]) ----------------
__global__ void k_vertex_gather(const unsigned int* __restrict__ Yeb, const float* __restrict__ risv,
                                const int* __restrict__ starts_v, const int* __restrict__ cnt_v,
                                const unsigned int* __restrict__ members,
                                float* __restrict__ out) {
  int wid = (blockIdx.x * 256 + threadIdx.x) >> 6;   // one wave per vertex
  int lane = threadIdx.x & 63;
  if (wid >= N_NODES) return;
  int beg = __builtin_amdgcn_readfirstlane(starts_v[wid]);
  int end = beg + __builtin_amdgcn_readfirstlane(cnt_v[wid]);
  float ax = 0.f, ay = 0.f;
  int i = beg;
  for (; i + 4 <= end; i += 4) {
    int e0 = members[i], e1 = members[i + 1], e2 = members[i + 2], e3 = members[i + 3];
    unsigned int y0 = Yeb[(size_t)e0 * DW + lane];
    unsigned int y1 = Yeb[(size_t)e1 * DW + lane];
    unsigned int y2 = Yeb[(size_t)e2 * DW + lane];
    unsigned int y3 = Yeb[(size_t)e3 * DW + lane];
    ax += __uint_as_float(y0 << 16) + __uint_as_float(y1 << 16)
        + __uint_as_float(y2 << 16) + __uint_as_float(y3 << 16);
    ay += __uint_as_float(y0 & 0xFFFF0000u) + __uint_as_float(y1 & 0xFFFF0000u)
        + __uint_as_float(y2 & 0xFFFF0000u) + __uint_as_float(y3 & 0xFFFF0000u);
  }
  for (; i < end; ++i) {
    int e = members[i];
    unsigned int y = Yeb[(size_t)e * DW + lane];
    ax += __uint_as_float(y << 16);
    ay += __uint_as_float(y & 0xFFFF0000u);
  }
  float s = risv[wid];
  float2 o; o.x = fmaxf(ax * s, 0.f); o.y = fmaxf(ay * s, 0.f);
  *(float2*)(out + (size_t)wid * D + lane * 2) = o;
}

extern "C" void kernel_launch(void* const* d_in, const int* in_sizes, int n_in,
                              void* d_out, int out_size, void* d_ws, size_t ws_size,
                              hipStream_t stream) {
  const float* X    = (const float*)d_in[0];
  const float* W    = (const float*)d_in[1];
  const float* bias = (const float*)d_in[2];
  const int* v_idx  = (const int*)d_in[3];
  const int* e_idx  = (const int*)d_in[4];
  float* out = (float*)d_out;

  char* p = (char*)d_ws;
  auto alloc = [&](size_t bytes) { char* r = p; p += (bytes + 255) & ~(size_t)255; return r; };
  unsigned int* Te  = (unsigned int*)alloc((size_t)NB * CAP_E * 4);
  unsigned int* Tv  = (unsigned int*)alloc((size_t)NB * CAP_V * 4);
  unsigned int* Xs  = (unsigned int*)alloc((size_t)N_NODES * DW * 4);
  unsigned int* Yeb = (unsigned int*)alloc((size_t)N_EDGES * DW * 4);
  float* Qe    = (float*)alloc((size_t)N_EDGES * D * 4);
  float* qv    = (float*)alloc((size_t)N_EDGES * 4);
  float* risv  = (float*)alloc((size_t)N_NODES * 4);
  float* invde = (float*)alloc((size_t)N_EDGES * 4);
  int* cnt_e    = (int*)alloc((size_t)N_EDGES * 4);
  int* cnt_v    = (int*)alloc((size_t)N_NODES * 4);
  int* starts_e = (int*)alloc((size_t)N_EDGES * 4);
  int* starts_v = (int*)alloc((size_t)N_NODES * 4);
  int* ce       = (int*)alloc(NB * 4);
  int* cv       = (int*)alloc(NB * 4);

  k_init<<<1, NB, 0, stream>>>(ce, cv);
  k_bin<<<P1_BLOCKS, 256, 0, stream>>>(v_idx, e_idx, ce, cv, Te, Tv);
  k_sort_e<<<NB, 256, 0, stream>>>(ce, Te, cnt_e, invde, starts_e);
  k_sort_v<<<NB, 256, 0, stream>>>(cv, Tv, cnt_v, risv, starts_v);
  k_prescale<<<(N_NODES * DW + 255) / 256, 256, 0, stream>>>(X, risv, Xs);

  k_edge_gather<<<N_EDGES / 4, 256, 0, stream>>>(Xs, risv, starts_e, cnt_e, Te, Qe, qv);
  k_gemm<<<N_EDGES / 16, 256, 0, stream>>>(Qe, qv, W, bias, invde, Yeb);
  k_vertex_gather<<<N_NODES / 4, 256, 0, stream>>>(Yeb, risv, starts_v, cnt_v, Tv, out);
}

// Round 4
// 307.564 us; speedup vs baseline: 2.4137x; 1.0048x over previous
//
#include <hip/hip_runtime.h>

#define N_NODES 100000
#define N_EDGES 20000
#define NNZ     1600000
#define D       128
#define DW      64                         // uints per bf16 row (2 ch per uint)

#define NB      256                        // buckets per side
#define CAP_E   8192
#define CAP_V   8192
#define SPAN_E  ((N_EDGES + NB - 1) / NB)  // 79
#define SPAN_V  ((N_NODES + NB - 1) / NB)  // 391
#define P1_CHUNK 8192
#define P1_BLOCKS ((NNZ + P1_CHUNK - 1) / P1_CHUNK)

__device__ __forceinline__ unsigned int pack_bf2(float lo, float hi) {
  unsigned int ul = __float_as_uint(lo), uh = __float_as_uint(hi);
  ul = (ul + 0x7FFFu + ((ul >> 16) & 1u)) >> 16;
  uh = (uh + 0x7FFFu + ((uh >> 16) & 1u)) & 0xFFFF0000u;
  return ul | uh;
}

// ---------------- init bucket cursors ----------------
__global__ void k_init(int* __restrict__ ce, int* __restrict__ cv) {
  int t = threadIdx.x;
  ce[t] = t * CAP_E;
  cv[t] = t * CAP_V;
}

// ---------------- pass 1: bin incidences ----------------
__global__ __launch_bounds__(256) void k_bin(const int* __restrict__ v_idx, const int* __restrict__ e_idx,
                                             int* __restrict__ ce, int* __restrict__ cv,
                                             unsigned int* __restrict__ Te, unsigned int* __restrict__ Tv) {
  __shared__ int he[NB], hv[NB], be[NB], bv[NB], le[NB], lv[NB];
  int t = threadIdx.x;
  he[t] = 0; hv[t] = 0; le[t] = 0; lv[t] = 0;
  __syncthreads();
  int base = blockIdx.x * P1_CHUNK;
  int v[32], e[32];
#pragma unroll
  for (int j = 0; j < 32; ++j) {
    int idx = base + j * 256 + t;
    if (idx < NNZ) {
      v[j] = v_idx[idx]; e[j] = e_idx[idx];
      atomicAdd(&he[e[j] / SPAN_E], 1);
      atomicAdd(&hv[v[j] / SPAN_V], 1);
    } else v[j] = -1;
  }
  __syncthreads();
  be[t] = he[t] ? atomicAdd(&ce[t], he[t]) : 0;
  bv[t] = hv[t] ? atomicAdd(&cv[t], hv[t]) : 0;
  __syncthreads();
#pragma unroll
  for (int j = 0; j < 32; ++j) {
    if (v[j] < 0) continue;
    int eb = e[j] / SPAN_E, vb = v[j] / SPAN_V;
    int se = be[eb] + atomicAdd(&le[eb], 1);
    int sv = bv[vb] + atomicAdd(&lv[vb], 1);
    if (se < (eb + 1) * CAP_E) Te[se] = ((unsigned)e[j] << 17) | (unsigned)v[j];
    if (sv < (vb + 1) * CAP_V) Tv[sv] = ((unsigned)v[j] << 15) | (unsigned)e[j];
  }
}

// ---------------- pass 2 (vertex side) — runs FIRST (produces risv for sort_e) ----------------
__global__ __launch_bounds__(256) void k_sort_v(const int* __restrict__ cv, unsigned int* __restrict__ Tv,
                                                int* __restrict__ cnt_v, float* __restrict__ risv,
                                                int* __restrict__ starts_v) {
  __shared__ unsigned int raw[CAP_V];
  __shared__ int hist[SPAN_V], lcur[SPAN_V], loff[SPAN_V + 1];
  int b = blockIdx.x, t = threadIdx.x;
  int v0 = b * SPAN_V;
  int span = N_NODES - v0; if (span > SPAN_V) span = SPAN_V;
  if (span <= 0) return;
  int n = cv[b] - b * CAP_V; if (n > CAP_V) n = CAP_V; if (n < 0) n = 0;
  for (int i = t; i < n; i += 256) raw[i] = Tv[b * CAP_V + i];
  for (int i = t; i < span; i += 256) { hist[i] = 0; lcur[i] = 0; }
  __syncthreads();
  for (int i = t; i < n; i += 256) atomicAdd(&hist[(int)(raw[i] >> 15) - v0], 1);
  __syncthreads();
  if (t == 0) { int run = 0; for (int i = 0; i < span; ++i) { loff[i] = run; run += hist[i]; } loff[span] = run; }
  __syncthreads();
  for (int i = t; i < n; i += 256) {
    unsigned int p = raw[i];
    int l = (int)(p >> 15) - v0;
    int slot = loff[l] + atomicAdd(&lcur[l], 1);
    Tv[b * CAP_V + slot] = p & 0x7FFFu;
  }
  for (int i = t; i < span; i += 256) {
    int d = hist[i];
    cnt_v[v0 + i] = d;
    risv[v0 + i] = d > 0 ? rsqrtf((float)d) : 0.0f;
    starts_v[v0 + i] = b * CAP_V + loff[i];
  }
}

// ---------------- pass 2 (edge side): sort + degrees + qv[e] = sum risv[v] ----------------
__global__ __launch_bounds__(256) void k_sort_e(const int* __restrict__ ce, unsigned int* __restrict__ Te,
                                                const float* __restrict__ risv,
                                                int* __restrict__ cnt_e, float* __restrict__ invde,
                                                int* __restrict__ starts_e, float* __restrict__ qv) {
  __shared__ unsigned int raw[CAP_E];
  __shared__ int hist[SPAN_E], lcur[SPAN_E], loff[SPAN_E + 1];
  __shared__ float qacc[SPAN_E];
  int b = blockIdx.x, t = threadIdx.x;
  int e0 = b * SPAN_E;
  int span = N_EDGES - e0; if (span > SPAN_E) span = SPAN_E;
  if (span <= 0) return;
  int n = ce[b] - b * CAP_E; if (n > CAP_E) n = CAP_E; if (n < 0) n = 0;
  for (int i = t; i < n; i += 256) raw[i] = Te[b * CAP_E + i];
  for (int i = t; i < span; i += 256) { hist[i] = 0; lcur[i] = 0; qacc[i] = 0.f; }
  __syncthreads();
  for (int i = t; i < n; i += 256) atomicAdd(&hist[(int)(raw[i] >> 17) - e0], 1);
  __syncthreads();
  if (t == 0) { int run = 0; for (int i = 0; i < span; ++i) { loff[i] = run; run += hist[i]; } loff[span] = run; }
  __syncthreads();
  for (int i = t; i < n; i += 256) {
    unsigned int p = raw[i];
    int l = (int)(p >> 17) - e0;
    int vtx = (int)(p & 0x1FFFFu);
    int slot = loff[l] + atomicAdd(&lcur[l], 1);
    Te[b * CAP_E + slot] = (unsigned)vtx;
    atomicAdd(&qacc[l], risv[vtx]);
  }
  __syncthreads();
  for (int i = t; i < span; i += 256) {
    int d = hist[i];
    cnt_e[e0 + i] = d;
    invde[e0 + i] = d > 0 ? 1.0f / (float)d : 0.0f;
    starts_e[e0 + i] = b * CAP_E + loff[i];
    qv[e0 + i] = qacc[i];
  }
}

// ---------------- prescale: Xs[v] = bf16(risv[v] * X[v]) ----------------
__global__ __launch_bounds__(256) void k_prescale(const float* __restrict__ X, const float* __restrict__ risv,
                                                  unsigned int* __restrict__ Xs) {
  int p = blockIdx.x * 256 + threadIdx.x;
  if (p >= N_NODES * DW) return;
  int v = p >> 6;
  float r = risv[v];
  float2 x = *(const float2*)(X + (size_t)p * 2);
  Xs[p] = pack_bf2(r * x.x, r * x.y);
}

// ---------------- phase A: Qeb[e] = bf16( sum Xs[v] ) ----------------
__global__ void k_edge_gather(const unsigned int* __restrict__ Xs,
                              const int* __restrict__ starts_e, const int* __restrict__ cnt_e,
                              const unsigned int* __restrict__ members,
                              unsigned int* __restrict__ Qeb) {
  int wid = (blockIdx.x * 256 + threadIdx.x) >> 6;   // one wave per edge
  int lane = threadIdx.x & 63;
  if (wid >= N_EDGES) return;
  int beg = __builtin_amdgcn_readfirstlane(starts_e[wid]);
  int end = beg + __builtin_amdgcn_readfirstlane(cnt_e[wid]);
  float ax = 0.f, ay = 0.f;
  int i = beg;
  for (; i + 16 <= end; i += 16) {
    int vv[16]; unsigned int xx[16];
#pragma unroll
    for (int j = 0; j < 16; ++j) vv[j] = members[i + j];
#pragma unroll
    for (int j = 0; j < 16; ++j) xx[j] = Xs[(size_t)vv[j] * DW + lane];
#pragma unroll
    for (int j = 0; j < 16; ++j) {
      ax += __uint_as_float(xx[j] << 16);
      ay += __uint_as_float(xx[j] & 0xFFFF0000u);
    }
  }
  if (i + 8 <= end) {
    int vv[8]; unsigned int xx[8];
#pragma unroll
    for (int j = 0; j < 8; ++j) vv[j] = members[i + j];
#pragma unroll
    for (int j = 0; j < 8; ++j) xx[j] = Xs[(size_t)vv[j] * DW + lane];
#pragma unroll
    for (int j = 0; j < 8; ++j) {
      ax += __uint_as_float(xx[j] << 16);
      ay += __uint_as_float(xx[j] & 0xFFFF0000u);
    }
    i += 8;
  }
  for (; i < end; ++i) {
    unsigned int x = Xs[(size_t)members[i] * DW + lane];
    ax += __uint_as_float(x << 16);
    ay += __uint_as_float(x & 0xFFFF0000u);
  }
  Qeb[(size_t)wid * DW + lane] = pack_bf2(ax, ay);
}

// ---------------- GEMM: Yeb[e] = bf16( invde[e] * (Qeb[e] @ W + qv[e] * b) ) ----------------
__global__ __launch_bounds__(256) void k_gemm(const unsigned int* __restrict__ Qeb, const float* __restrict__ qv,
                                              const float* __restrict__ W, const float* __restrict__ bias,
                                              const float* __restrict__ invde, unsigned int* __restrict__ Yeb) {
  __shared__ float Wl[D * D];
  __shared__ float bl[D];
  __shared__ float Ql[16][130];
  int tid = threadIdx.x;
  const float4* W4 = (const float4*)W;
  float4* Wl4 = (float4*)Wl;
#pragma unroll
  for (int j = 0; j < 16; ++j) Wl4[tid + 256 * j] = W4[tid + 256 * j];
  if (tid < 32) ((float4*)bl)[tid] = ((const float4*)bias)[tid];
  int row0 = blockIdx.x * 16;
  const unsigned int* Q8 = Qeb + (size_t)row0 * DW;
#pragma unroll
  for (int j = 0; j < 4; ++j) {
    int idx = tid + 256 * j;          // 0..1023 (16 rows x 64 uints)
    int r = idx >> 6, c = idx & 63;
    unsigned int u = Q8[idx];
    Ql[r][2 * c]     = __uint_as_float(u << 16);
    Ql[r][2 * c + 1] = __uint_as_float(u & 0xFFFF0000u);
  }
  __syncthreads();
  int ty = tid >> 4, tx = tid & 15;
  float acc[8];
#pragma unroll
  for (int j = 0; j < 8; ++j) acc[j] = 0.f;
#pragma unroll 4
  for (int k = 0; k < D; ++k) {
    float xv = Ql[ty][k];
    const float* wr = Wl + k * D + tx * 8;
#pragma unroll
    for (int j = 0; j < 8; ++j) acc[j] += xv * wr[j];
  }
  int row = row0 + ty;
  float s = invde[row]; float q = qv[row];
  unsigned int* orow = Yeb + (size_t)row * DW + tx * 4;
#pragma unroll
  for (int j = 0; j < 4; ++j) {
    float lo = s * (acc[2 * j]     + q * bl[tx * 8 + 2 * j]);
    float hi = s * (acc[2 * j + 1] + q * bl[tx * 8 + 2 * j + 1]);
    orow[j] = pack_bf2(lo, hi);
  }
}

// ---------------- phase B: out[v] = relu(risv[v] * sum Yeb[e]) ----------------
__global__ void k_vertex_gather(const unsigned int* __restrict__ Yeb, const float* __restrict__ risv,
                                const int* __restrict__ starts_v, const int* __restrict__ cnt_v,
                                const unsigned int* __restrict__ members,
                                float* __restrict__ out) {
  int wid = (blockIdx.x * 256 + threadIdx.x) >> 6;   // one wave per vertex
  int lane = threadIdx.x & 63;
  if (wid >= N_NODES) return;
  int beg = __builtin_amdgcn_readfirstlane(starts_v[wid]);
  int end = beg + __builtin_amdgcn_readfirstlane(cnt_v[wid]);
  float ax = 0.f, ay = 0.f;
  int i = beg;
  for (; i + 8 <= end; i += 8) {
    int ee[8]; unsigned int yy[8];
#pragma unroll
    for (int j = 0; j < 8; ++j) ee[j] = members[i + j];
#pragma unroll
    for (int j = 0; j < 8; ++j) yy[j] = Yeb[(size_t)ee[j] * DW + lane];
#pragma unroll
    for (int j = 0; j < 8; ++j) {
      ax += __uint_as_float(yy[j] << 16);
      ay += __uint_as_float(yy[j] & 0xFFFF0000u);
    }
  }
  for (; i < end; ++i) {
    unsigned int y = Yeb[(size_t)members[i] * DW + lane];
    ax += __uint_as_float(y << 16);
    ay += __uint_as_float(y & 0xFFFF0000u);
  }
  float s = risv[wid];
  float2 o; o.x = fmaxf(ax * s, 0.f); o.y = fmaxf(ay * s, 0.f);
  *(float2*)(out + (size_t)wid * D + lane * 2) = o;
}

extern "C" void kernel_launch(void* const* d_in, const int* in_sizes, int n_in,
                              void* d_out, int out_size, void* d_ws, size_t ws_size,
                              hipStream_t stream) {
  const float* X    = (const float*)d_in[0];
  const float* W    = (const float*)d_in[1];
  const float* bias = (const float*)d_in[2];
  const int* v_idx  = (const int*)d_in[3];
  const int* e_idx  = (const int*)d_in[4];
  float* out = (float*)d_out;

  char* p = (char*)d_ws;
  auto alloc = [&](size_t bytes) { char* r = p; p += (bytes + 255) & ~(size_t)255; return r; };
  unsigned int* Te  = (unsigned int*)alloc((size_t)NB * CAP_E * 4);
  unsigned int* Tv  = (unsigned int*)alloc((size_t)NB * CAP_V * 4);
  unsigned int* Xs  = (unsigned int*)alloc((size_t)N_NODES * DW * 4);
  unsigned int* Qeb = (unsigned int*)alloc((size_t)N_EDGES * DW * 4);
  unsigned int* Yeb = (unsigned int*)alloc((size_t)N_EDGES * DW * 4);
  float* qv    = (float*)alloc((size_t)N_EDGES * 4);
  float* risv  = (float*)alloc((size_t)N_NODES * 4);
  float* invde = (float*)alloc((size_t)N_EDGES * 4);
  int* cnt_e    = (int*)alloc((size_t)N_EDGES * 4);
  int* cnt_v    = (int*)alloc((size_t)N_NODES * 4);
  int* starts_e = (int*)alloc((size_t)N_EDGES * 4);
  int* starts_v = (int*)alloc((size_t)N_NODES * 4);
  int* ce       = (int*)alloc(NB * 4);
  int* cv       = (int*)alloc(NB * 4);

  k_init<<<1, NB, 0, stream>>>(ce, cv);
  k_bin<<<P1_BLOCKS, 256, 0, stream>>>(v_idx, e_idx, ce, cv, Te, Tv);
  k_sort_v<<<NB, 256, 0, stream>>>(cv, Tv, cnt_v, risv, starts_v);
  k_sort_e<<<NB, 256, 0, stream>>>(ce, Te, risv, cnt_e, invde, starts_e, qv);
  k_prescale<<<(N_NODES * DW + 255) / 256, 256, 0, stream>>>(X, risv, Xs);

  k_edge_gather<<<N_EDGES / 4, 256, 0, stream>>>(Xs, starts_e, cnt_e, Te, Qeb);
  k_gemm<<<N_EDGES / 16, 256, 0, stream>>>(Qeb, qv, W, bias, invde, Yeb);
  k_vertex_gather<<<N_NODES / 4, 256, 0, stream>>>(Yeb, risv, starts_v, cnt_v, Tv, out);
}